// Round 1
// baseline (698.720 us; speedup 1.0000x reference)
//
#include <hip/hip_runtime.h>

#define N_NODES 100000
#define N_EDGES 1600000
#define N_GRAPHS 1024
#define DIM_IN 128
#define D1 100
#define D2 20
#define DIM_SF 32
#define DF1 128
#define DF2 32
#define DOUT 8
#define EPS 1e-5f

// ---------------- CSR build (by dst) ----------------
__global__ void k_count(const int* __restrict__ dst, int* __restrict__ deg) {
  int e = blockIdx.x * 256 + threadIdx.x;
  if (e < N_EDGES) atomicAdd(&deg[dst[e]], 1);
}

#define SCAN_CHUNK 2048
#define SCAN_NB 49   // ceil(100000/2048)

__global__ void k_scan1(const int* __restrict__ deg, int* __restrict__ blocksum) {
  __shared__ int lds[256];
  int t = threadIdx.x, b = blockIdx.x;
  int base = b * SCAN_CHUNK + t * 8;
  int s = 0;
#pragma unroll
  for (int j = 0; j < 8; j++) { int i = base + j; if (i < N_NODES) s += deg[i]; }
  lds[t] = s; __syncthreads();
  for (int off = 128; off > 0; off >>= 1) {
    if (t < off) lds[t] += lds[t + off];
    __syncthreads();
  }
  if (t == 0) blocksum[b] = lds[0];
}

__global__ void k_scan2(const int* __restrict__ blocksum, int* __restrict__ blockoff) {
  int l = threadIdx.x;
  int v = (l < SCAN_NB) ? blocksum[l] : 0;
  int incl = v;
  for (int s = 1; s < 64; s <<= 1) {
    int x = __shfl_up(incl, s);
    if (l >= s) incl += x;
  }
  if (l < SCAN_NB) blockoff[l] = incl - v;
}

__global__ void k_scan3(const int* __restrict__ deg, const int* __restrict__ blockoff,
                        int* __restrict__ row_off, int* __restrict__ cursor) {
  __shared__ int lds[256];
  int t = threadIdx.x, b = blockIdx.x;
  int base = b * SCAN_CHUNK + t * 8;
  int v[8]; int s = 0;
#pragma unroll
  for (int j = 0; j < 8; j++) { int i = base + j; v[j] = (i < N_NODES) ? deg[i] : 0; s += v[j]; }
  int mine = s;
  lds[t] = mine; __syncthreads();
  for (int off = 1; off < 256; off <<= 1) {     // Hillis-Steele inclusive
    int x = (t >= off) ? lds[t - off] : 0;
    __syncthreads();
    lds[t] += x;
    __syncthreads();
  }
  int run = blockoff[b] + lds[t] - mine;        // exclusive prefix for this thread
#pragma unroll
  for (int j = 0; j < 8; j++) {
    int i = base + j;
    if (i < N_NODES) { row_off[i] = run; cursor[i] = run; }
    run += v[j];
  }
}

__global__ void k_scatter(const int* __restrict__ src, const int* __restrict__ dst,
                          int* __restrict__ cursor, int* __restrict__ csr) {
  int e = blockIdx.x * 256 + threadIdx.x;
  if (e < N_EDGES) {
    int p = atomicAdd(&cursor[dst[e]], 1);
    csr[p] = src[e];
  }
}

// ---------------- p1 = feat @ W1  (no bias; bias after aggregation) ----------------
__global__ void __launch_bounds__(256) k_gemm1(const float* __restrict__ feat,
                                               const float* __restrict__ W1,
                                               float* __restrict__ p1) {
  __shared__ float w1s[DIM_IN * D1];   // 12800 floats = 51.2 KB
  int t = threadIdx.x;
  for (int i = t; i < DIM_IN * D1; i += 256) w1s[i] = W1[i];
  __syncthreads();
  int idx = blockIdx.x * 256 + t;
  int node = idx / 25, q = idx % 25;   // 25 groups of 4 cols
  if (node >= N_NODES) return;
  int c0 = q * 4;
  float4 acc = make_float4(0.f, 0.f, 0.f, 0.f);
  const float* frow = feat + node * DIM_IN;
  for (int k = 0; k < DIM_IN; k += 4) {
    float4 f = *(const float4*)(frow + k);
    float4 w0 = *(const float4*)&w1s[(k + 0) * D1 + c0];
    float4 w1 = *(const float4*)&w1s[(k + 1) * D1 + c0];
    float4 w2 = *(const float4*)&w1s[(k + 2) * D1 + c0];
    float4 w3 = *(const float4*)&w1s[(k + 3) * D1 + c0];
    acc.x += f.x * w0.x + f.y * w1.x + f.z * w2.x + f.w * w3.x;
    acc.y += f.x * w0.y + f.y * w1.y + f.z * w2.y + f.w * w3.y;
    acc.z += f.x * w0.z + f.y * w1.z + f.z * w2.z + f.w * w3.z;
    acc.w += f.x * w0.w + f.y * w1.w + f.z * w2.w + f.w * w3.w;
  }
  *(float4*)&p1[node * D1 + c0] = acc;
}

// ---------- agg1 (mean over in-edges of p1, fallback p1[n]) + b1 + relu + GEMM2 -> p2 ----------
__global__ void __launch_bounds__(256) k_agg1(const float* __restrict__ p1,
                                              const int* __restrict__ deg,
                                              const int* __restrict__ row_off,
                                              const int* __restrict__ csr,
                                              const float* __restrict__ b1,
                                              const float* __restrict__ W2,
                                              float* __restrict__ p2) {
  __shared__ float w2s[D1 * D2];   // 2000 floats
  __shared__ float b1s[D1];
  __shared__ float hbuf[4][104];
  int t = threadIdx.x;
  for (int i = t; i < D1 * D2; i += 256) w2s[i] = W2[i];
  if (t < D1) b1s[t] = b1[t];
  __syncthreads();
  int w = t >> 6, lane = t & 63;
  int n = blockIdx.x * 4 + w;          // grid = 25000 -> exactly N_NODES
  int d = deg[n], ro = row_off[n];
  bool has2 = lane < (D1 - 64);
  int c1 = lane + 64;
  float a0 = 0.f, a1 = 0.f;
  if (d > 0) {
    for (int base = 0; base < d; base += 64) {
      int m = d - base; if (m > 64) m = 64;
      int sv = (lane < m) ? csr[ro + base + lane] : 0;   // cooperative index prefetch
      int j = 0;
      for (; j + 1 < m; j += 2) {
        int s0 = __shfl(sv, j), s1 = __shfl(sv, j + 1);
        const float* r0 = p1 + s0 * D1;
        const float* r1 = p1 + s1 * D1;
        float x0 = r0[lane], x1 = r1[lane];
        float y0 = 0.f, y1v = 0.f;
        if (has2) { y0 = r0[c1]; y1v = r1[c1]; }
        a0 += x0 + x1;
        a1 += y0 + y1v;
      }
      if (j < m) {
        int s0 = __shfl(sv, j);
        a0 += p1[s0 * D1 + lane];
        if (has2) a1 += p1[s0 * D1 + c1];
      }
    }
    float inv = 1.0f / (float)d;
    a0 *= inv; a1 *= inv;
  } else {
    a0 = p1[n * D1 + lane];
    if (has2) a1 = p1[n * D1 + c1];
  }
  hbuf[w][lane] = fmaxf(a0 + b1s[lane], 0.f);
  if (has2) hbuf[w][c1] = fmaxf(a1 + b1s[c1], 0.f);
  __syncthreads();
  if (lane < D2) {
    float acc = 0.f;
#pragma unroll 4
    for (int c = 0; c < D1; c++) acc += hbuf[w][c] * w2s[c * D2 + lane];
    p2[n * D2 + lane] = acc;   // no bias here (added after agg2's where)
  }
}

// ---------- agg2 (mean of p2, fallback p2[n]) + b2 + relu + graph-pool atomics ----------
__global__ void k_agg2(const float* __restrict__ p2, const int* __restrict__ deg,
                       const int* __restrict__ row_off, const int* __restrict__ csr,
                       const float* __restrict__ b2, const int* __restrict__ n2g,
                       float* __restrict__ hg_sum, int* __restrict__ gcnt) {
  int idx = blockIdx.x * 256 + threadIdx.x;
  int n = idx / D2, c = idx % D2;
  if (n >= N_NODES) return;
  int d = deg[n], ro = row_off[n];
  float acc = 0.f, accb = 0.f;
  if (d > 0) {
    int e = 0;
    for (; e + 1 < d; e += 2) {
      int s0 = csr[ro + e], s1 = csr[ro + e + 1];
      acc += p2[s0 * D2 + c];
      accb += p2[s1 * D2 + c];
    }
    if (e < d) acc += p2[csr[ro + e] * D2 + c];
    acc = (acc + accb) / (float)d;
  } else {
    acc = p2[n * D2 + c];
  }
  float v = fmaxf(acc + b2[c], 0.f);
  int g = n2g[n];
  atomicAdd(&hg_sum[g * D2 + c], v);
  if (c == 0) atomicAdd(&gcnt[g], 1);
}

// ---------- head: hg = hg_sum/cnt; fused = kron(hg, sf); y1 = fused@Wf1 + bf1 ----------
__global__ void __launch_bounds__(128) k_mlp1(const float* __restrict__ hg_sum,
                                              const int* __restrict__ gcnt,
                                              const float* __restrict__ sf,
                                              const float* __restrict__ Wf1,
                                              const float* __restrict__ bf1,
                                              float* __restrict__ y1) {
  __shared__ float prod[D2 * DIM_SF];   // 640
  __shared__ float hgl[D2], sfl[DIM_SF];
  int g = blockIdx.x, t = threadIdx.x;
  float cnt = (float)gcnt[g]; if (cnt < 1.f) cnt = 1.f;
  if (t < D2) hgl[t] = hg_sum[g * D2 + t] / cnt;
  if (t < DIM_SF) sfl[t] = sf[g * DIM_SF + t];
  __syncthreads();
  for (int i = t; i < D2 * DIM_SF; i += 128) prod[i] = hgl[i >> 5] * sfl[i & 31];
  __syncthreads();
  float acc = bf1[t];
#pragma unroll 4
  for (int k = 0; k < D2 * DIM_SF; k++) acc += prod[k] * Wf1[k * DF1 + t];
  y1[g * DF1 + t] = acc;
}

// ---------- BN batch stats (training mode, biased variance) ----------
__global__ void k_bnstats(const float* __restrict__ x, int ld,
                          float* __restrict__ mu, float* __restrict__ rstd) {
  __shared__ float ssum[256], ssq[256];
  int c = blockIdx.x, t = threadIdx.x;
  float s = 0.f, q = 0.f;
  for (int r = t; r < N_GRAPHS; r += 256) { float v = x[r * ld + c]; s += v; q += v * v; }
  ssum[t] = s; ssq[t] = q; __syncthreads();
  for (int off = 128; off > 0; off >>= 1) {
    if (t < off) { ssum[t] += ssum[t + off]; ssq[t] += ssq[t + off]; }
    __syncthreads();
  }
  if (t == 0) {
    float m = ssum[0] / (float)N_GRAPHS;
    float var = ssq[0] / (float)N_GRAPHS - m * m;
    mu[c] = m;
    rstd[c] = rsqrtf(var + EPS);
  }
}

// ---------- y2 = relu(bn1(y1)) @ Wf2 + bf2 ----------
__global__ void k_mlp2(const float* __restrict__ y1, const float* __restrict__ mu1,
                       const float* __restrict__ rstd1, const float* __restrict__ g1,
                       const float* __restrict__ be1, const float* __restrict__ Wf2,
                       const float* __restrict__ bf2, float* __restrict__ y2) {
  int idx = blockIdx.x * 256 + threadIdx.x;   // 1024*32
  int g = idx >> 5, o = idx & 31;
  float acc = bf2[o];
  for (int k = 0; k < DF1; k++) {
    float x = (y1[g * DF1 + k] - mu1[k]) * rstd1[k] * g1[k] + be1[k];
    x = fmaxf(x, 0.f);
    acc += x * Wf2[k * DF2 + o];
  }
  y2[g * DF2 + o] = acc;
}

// ---------- out = relu(bn2(y2)) @ Wf3 + bf3 ----------
__global__ void k_mlp3(const float* __restrict__ y2, const float* __restrict__ mu2,
                       const float* __restrict__ rstd2, const float* __restrict__ g2,
                       const float* __restrict__ be2, const float* __restrict__ Wf3,
                       const float* __restrict__ bf3, float* __restrict__ out) {
  int idx = blockIdx.x * 256 + threadIdx.x;   // 1024*8
  int g = idx >> 3, o = idx & 7;
  float acc = bf3[o];
  for (int k = 0; k < DF2; k++) {
    float x = (y2[g * DF2 + k] - mu2[k]) * rstd2[k] * g2[k] + be2[k];
    x = fmaxf(x, 0.f);
    acc += x * Wf3[k * DOUT + o];
  }
  out[g * DOUT + o] = acc;
}

extern "C" void kernel_launch(void* const* d_in, const int* in_sizes, int n_in,
                              void* d_out, int out_size, void* d_ws, size_t ws_size,
                              hipStream_t stream) {
  const float* feat = (const float*)d_in[0];
  const float* sf   = (const float*)d_in[1];
  const int*   src  = (const int*)d_in[2];
  const int*   dst  = (const int*)d_in[3];
  const int*   n2g  = (const int*)d_in[4];
  const float* W1   = (const float*)d_in[5];
  const float* b1   = (const float*)d_in[6];
  const float* W2   = (const float*)d_in[7];
  const float* b2   = (const float*)d_in[8];
  const float* Wf1  = (const float*)d_in[9];
  const float* bf1  = (const float*)d_in[10];
  const float* g1   = (const float*)d_in[11];
  const float* be1  = (const float*)d_in[12];
  const float* Wf2  = (const float*)d_in[13];
  const float* bf2  = (const float*)d_in[14];
  const float* g2   = (const float*)d_in[15];
  const float* be2  = (const float*)d_in[16];
  const float* Wf3  = (const float*)d_in[17];
  const float* bf3  = (const float*)d_in[18];
  float* out = (float*)d_out;

  char* ws = (char*)d_ws;
  size_t off = 0;
  auto alloc = [&](size_t bytes) -> void* {
    void* p = ws + off;
    off = (off + bytes + 255) & ~(size_t)255;
    return p;
  };
  // zero-init region first (deg, gcnt, hg_sum) — one memset covers it
  int*   deg     = (int*)alloc(N_NODES * 4);
  int*   gcnt    = (int*)alloc(N_GRAPHS * 4);
  float* hg_sum  = (float*)alloc(N_GRAPHS * D2 * 4);
  size_t zero_bytes = off;
  int*   row_off = (int*)alloc(N_NODES * 4);
  int*   cursor  = (int*)alloc(N_NODES * 4);
  int*   blocksum= (int*)alloc(64 * 4);
  int*   blockoff= (int*)alloc(64 * 4);
  int*   csr     = (int*)alloc((size_t)N_EDGES * 4);
  float* p1      = (float*)alloc((size_t)N_NODES * D1 * 4);
  float* p2      = (float*)alloc((size_t)N_NODES * D2 * 4);
  float* y1      = (float*)alloc((size_t)N_GRAPHS * DF1 * 4);
  float* y2      = (float*)alloc((size_t)N_GRAPHS * DF2 * 4);
  float* mu1     = (float*)alloc(DF1 * 4);
  float* rstd1   = (float*)alloc(DF1 * 4);
  float* mu2     = (float*)alloc(DF2 * 4);
  float* rstd2   = (float*)alloc(DF2 * 4);

  hipMemsetAsync(d_ws, 0, zero_bytes, stream);

  k_count<<<N_EDGES / 256, 256, 0, stream>>>(dst, deg);
  k_scan1<<<SCAN_NB, 256, 0, stream>>>(deg, blocksum);
  k_scan2<<<1, 64, 0, stream>>>(blocksum, blockoff);
  k_scan3<<<SCAN_NB, 256, 0, stream>>>(deg, blockoff, row_off, cursor);
  k_scatter<<<N_EDGES / 256, 256, 0, stream>>>(src, dst, cursor, csr);
  k_gemm1<<<(N_NODES * 25 + 255) / 256, 256, 0, stream>>>(feat, W1, p1);
  k_agg1<<<N_NODES / 4, 256, 0, stream>>>(p1, deg, row_off, csr, b1, W2, p2);
  k_agg2<<<(N_NODES * D2 + 255) / 256, 256, 0, stream>>>(p2, deg, row_off, csr, b2, n2g, hg_sum, gcnt);
  k_mlp1<<<N_GRAPHS, 128, 0, stream>>>(hg_sum, gcnt, sf, Wf1, bf1, y1);
  k_bnstats<<<DF1, 256, 0, stream>>>(y1, DF1, mu1, rstd1);
  k_mlp2<<<(N_GRAPHS * DF2) / 256, 256, 0, stream>>>(y1, mu1, rstd1, g1, be1, Wf2, bf2, y2);
  k_bnstats<<<DF2, 256, 0, stream>>>(y2, DF2, mu2, rstd2);
  k_mlp3<<<(N_GRAPHS * DOUT) / 256, 256, 0, stream>>>(y2, mu2, rstd2, g2, be2, Wf3, bf3, out);
}

// Round 2
// 641.057 us; speedup vs baseline: 1.0900x; 1.0900x over previous
//
#include <hip/hip_runtime.h>
#include <hip/hip_fp16.h>

#define N_NODES 100000
#define N_EDGES 1600000
#define N_GRAPHS 1024
#define DIM_IN 128
#define D1 100
#define D2 20
#define DIM_SF 32
#define DF1 128
#define DF2 32
#define DOUT 8
#define EPS 1e-5f

// ---------------- CSR build (by dst) ----------------
__global__ void k_count(const int* __restrict__ dst, int* __restrict__ deg) {
  int e = blockIdx.x * 256 + threadIdx.x;
  if (e < N_EDGES) atomicAdd(&deg[dst[e]], 1);
}

#define SCAN_CHUNK 2048
#define SCAN_NB 49   // ceil(100000/2048)

__global__ void k_scan1(const int* __restrict__ deg, int* __restrict__ blocksum) {
  __shared__ int lds[256];
  int t = threadIdx.x, b = blockIdx.x;
  int base = b * SCAN_CHUNK + t * 8;
  int s = 0;
#pragma unroll
  for (int j = 0; j < 8; j++) { int i = base + j; if (i < N_NODES) s += deg[i]; }
  lds[t] = s; __syncthreads();
  for (int off = 128; off > 0; off >>= 1) {
    if (t < off) lds[t] += lds[t + off];
    __syncthreads();
  }
  if (t == 0) blocksum[b] = lds[0];
}

__global__ void k_scan2(const int* __restrict__ blocksum, int* __restrict__ blockoff) {
  int l = threadIdx.x;
  int v = (l < SCAN_NB) ? blocksum[l] : 0;
  int incl = v;
  for (int s = 1; s < 64; s <<= 1) {
    int x = __shfl_up(incl, s);
    if (l >= s) incl += x;
  }
  if (l < SCAN_NB) blockoff[l] = incl - v;
}

__global__ void k_scan3(const int* __restrict__ deg, const int* __restrict__ blockoff,
                        int* __restrict__ row_off, int* __restrict__ cursor) {
  __shared__ int lds[256];
  int t = threadIdx.x, b = blockIdx.x;
  int base = b * SCAN_CHUNK + t * 8;
  int v[8]; int s = 0;
#pragma unroll
  for (int j = 0; j < 8; j++) { int i = base + j; v[j] = (i < N_NODES) ? deg[i] : 0; s += v[j]; }
  int mine = s;
  lds[t] = mine; __syncthreads();
  for (int off = 1; off < 256; off <<= 1) {     // Hillis-Steele inclusive
    int x = (t >= off) ? lds[t - off] : 0;
    __syncthreads();
    lds[t] += x;
    __syncthreads();
  }
  int run = blockoff[b] + lds[t] - mine;        // exclusive prefix for this thread
#pragma unroll
  for (int j = 0; j < 8; j++) {
    int i = base + j;
    if (i < N_NODES) { row_off[i] = run; cursor[i] = run; }
    run += v[j];
  }
}

__global__ void k_scatter(const int* __restrict__ src, const int* __restrict__ dst,
                          int* __restrict__ cursor, int* __restrict__ csr) {
  int e = blockIdx.x * 256 + threadIdx.x;
  if (e < N_EDGES) {
    int p = atomicAdd(&cursor[dst[e]], 1);
    csr[p] = src[e];
  }
}

// ---------------- p1 = fp16(feat @ W1)  (bias applied after aggregation) ----------------
// Register-blocked: each thread computes 4 nodes x 4 cols (64 FMA per 4 LDS float4 reads
// -> VALU-bound). Block: 250 active threads = 10 node-groups x 25 col-groups = 40 nodes.
__global__ void __launch_bounds__(256) k_gemm1(const float* __restrict__ feat,
                                               const float* __restrict__ W1,
                                               __half* __restrict__ p1h) {
  __shared__ float w1s[DIM_IN * D1];   // 51.2 KB -> 3 blocks/CU
  int t = threadIdx.x;
  for (int i = t; i < DIM_IN * D1; i += 256) w1s[i] = W1[i];
  __syncthreads();
  if (t >= 250) return;
  int q = t % 25, ng = t / 25;
  int n0 = blockIdx.x * 40 + ng * 4;   // grid 2500 -> exactly 100000 nodes
  int c0 = q * 4;
  float acc[4][4] = {{0.f}};
  const float* f0 = feat + (size_t)n0 * DIM_IN;
  for (int k = 0; k < DIM_IN; k += 4) {
    float4 w0 = *(const float4*)&w1s[(k + 0) * D1 + c0];
    float4 w1 = *(const float4*)&w1s[(k + 1) * D1 + c0];
    float4 w2 = *(const float4*)&w1s[(k + 2) * D1 + c0];
    float4 w3 = *(const float4*)&w1s[(k + 3) * D1 + c0];
#pragma unroll
    for (int j = 0; j < 4; j++) {
      float4 f = *(const float4*)(f0 + j * DIM_IN + k);
      acc[j][0] += f.x * w0.x + f.y * w1.x + f.z * w2.x + f.w * w3.x;
      acc[j][1] += f.x * w0.y + f.y * w1.y + f.z * w2.y + f.w * w3.y;
      acc[j][2] += f.x * w0.z + f.y * w1.z + f.z * w2.z + f.w * w3.z;
      acc[j][3] += f.x * w0.w + f.y * w1.w + f.z * w2.w + f.w * w3.w;
    }
  }
#pragma unroll
  for (int j = 0; j < 4; j++) {
    __half2* d2 = (__half2*)(p1h + (size_t)(n0 + j) * D1 + c0);  // c0%4==0 -> 8B aligned
    d2[0] = __floats2half2_rn(acc[j][0], acc[j][1]);
    d2[1] = __floats2half2_rn(acc[j][2], acc[j][3]);
  }
}

// ---------- agg1 (mean of fp16 p1 over in-edges, fallback p1[n]) + b1 + relu + GEMM2 -> fp16 p2 ----------
// One wave per node. Lanes 0..49 each own a half2 column pair (100 cols = 50 half2).
__global__ void __launch_bounds__(256) k_agg1(const __half* __restrict__ p1h,
                                              const int* __restrict__ deg,
                                              const int* __restrict__ row_off,
                                              const int* __restrict__ csr,
                                              const float* __restrict__ b1,
                                              const float* __restrict__ W2,
                                              __half* __restrict__ p2h) {
  __shared__ float w2s[D1 * D2];   // 8 KB
  __shared__ float b1s[D1];
  __shared__ float hbuf[4][104];
  int t = threadIdx.x;
  for (int i = t; i < D1 * D2; i += 256) w2s[i] = W2[i];
  if (t < D1) b1s[t] = b1[t];
  __syncthreads();
  int w = t >> 6, lane = t & 63;
  int n = blockIdx.x * 4 + w;          // grid = 25000 -> exactly N_NODES
  int d = deg[n], ro = row_off[n];
  bool act = lane < 50;
  float ax = 0.f, ay = 0.f;
  if (d > 0) {
    for (int base = 0; base < d; base += 64) {
      int m = d - base; if (m > 64) m = 64;
      int sv = (lane < m) ? csr[ro + base + lane] : 0;   // cooperative index prefetch
      int j = 0;
      for (; j + 3 < m; j += 4) {
        int s0 = __shfl(sv, j), s1 = __shfl(sv, j + 1);
        int s2 = __shfl(sv, j + 2), s3 = __shfl(sv, j + 3);
        if (act) {
          float2 v0 = __half22float2(((const __half2*)(p1h + (size_t)s0 * D1))[lane]);
          float2 v1 = __half22float2(((const __half2*)(p1h + (size_t)s1 * D1))[lane]);
          float2 v2 = __half22float2(((const __half2*)(p1h + (size_t)s2 * D1))[lane]);
          float2 v3 = __half22float2(((const __half2*)(p1h + (size_t)s3 * D1))[lane]);
          ax += (v0.x + v1.x) + (v2.x + v3.x);
          ay += (v0.y + v1.y) + (v2.y + v3.y);
        }
      }
      for (; j < m; j++) {
        int s0 = __shfl(sv, j);
        if (act) {
          float2 v0 = __half22float2(((const __half2*)(p1h + (size_t)s0 * D1))[lane]);
          ax += v0.x; ay += v0.y;
        }
      }
    }
    float inv = 1.0f / (float)d;
    ax *= inv; ay *= inv;
  } else if (act) {
    float2 v = __half22float2(((const __half2*)(p1h + (size_t)n * D1))[lane]);
    ax = v.x; ay = v.y;
  }
  if (act) {
    int c = lane * 2;
    hbuf[w][c]     = fmaxf(ax + b1s[c], 0.f);
    hbuf[w][c + 1] = fmaxf(ay + b1s[c + 1], 0.f);
  }
  __syncthreads();
  if (lane < D2) {
    float acc = 0.f;
#pragma unroll 4
    for (int c = 0; c < D1; c++) acc += hbuf[w][c] * w2s[c * D2 + lane];
    p2h[(size_t)n * D2 + lane] = __float2half_rn(acc);   // bias b2 added in agg2
  }
}

// ---------- agg2 (mean of fp16 p2, fallback p2[n]) + b2 + relu + graph-pool atomics ----------
__global__ void k_agg2(const __half* __restrict__ p2h, const int* __restrict__ deg,
                       const int* __restrict__ row_off, const int* __restrict__ csr,
                       const float* __restrict__ b2, const int* __restrict__ n2g,
                       float* __restrict__ hg_sum, int* __restrict__ gcnt) {
  int idx = blockIdx.x * 256 + threadIdx.x;
  int n = idx / D2, c = idx % D2;
  if (n >= N_NODES) return;
  int d = deg[n], ro = row_off[n];
  float acc = 0.f;
  if (d > 0) {
    float a0 = 0.f, a1 = 0.f, a2 = 0.f, a3 = 0.f;
    int e = 0;
    for (; e + 3 < d; e += 4) {
      int s0 = csr[ro + e],     s1 = csr[ro + e + 1];
      int s2 = csr[ro + e + 2], s3 = csr[ro + e + 3];
      a0 += __half2float(p2h[(size_t)s0 * D2 + c]);
      a1 += __half2float(p2h[(size_t)s1 * D2 + c]);
      a2 += __half2float(p2h[(size_t)s2 * D2 + c]);
      a3 += __half2float(p2h[(size_t)s3 * D2 + c]);
    }
    for (; e < d; e++) a0 += __half2float(p2h[(size_t)csr[ro + e] * D2 + c]);
    acc = ((a0 + a1) + (a2 + a3)) / (float)d;
  } else {
    acc = __half2float(p2h[(size_t)n * D2 + c]);
  }
  float v = fmaxf(acc + b2[c], 0.f);
  int g = n2g[n];
  atomicAdd(&hg_sum[g * D2 + c], v);
  if (c == 0) atomicAdd(&gcnt[g], 1);
}

// ---------- head: hg = hg_sum/cnt; fused = kron(hg, sf); y1 = fused@Wf1 + bf1 ----------
__global__ void __launch_bounds__(128) k_mlp1(const float* __restrict__ hg_sum,
                                              const int* __restrict__ gcnt,
                                              const float* __restrict__ sf,
                                              const float* __restrict__ Wf1,
                                              const float* __restrict__ bf1,
                                              float* __restrict__ y1) {
  __shared__ float prod[D2 * DIM_SF];   // 640
  __shared__ float hgl[D2], sfl[DIM_SF];
  int g = blockIdx.x, t = threadIdx.x;
  float cnt = (float)gcnt[g]; if (cnt < 1.f) cnt = 1.f;
  if (t < D2) hgl[t] = hg_sum[g * D2 + t] / cnt;
  if (t < DIM_SF) sfl[t] = sf[g * DIM_SF + t];
  __syncthreads();
  for (int i = t; i < D2 * DIM_SF; i += 128) prod[i] = hgl[i >> 5] * sfl[i & 31];
  __syncthreads();
  float acc = bf1[t];
#pragma unroll 4
  for (int k = 0; k < D2 * DIM_SF; k++) acc += prod[k] * Wf1[k * DF1 + t];
  y1[g * DF1 + t] = acc;
}

// ---------- BN batch stats (training mode, biased variance) ----------
__global__ void k_bnstats(const float* __restrict__ x, int ld,
                          float* __restrict__ mu, float* __restrict__ rstd) {
  __shared__ float ssum[256], ssq[256];
  int c = blockIdx.x, t = threadIdx.x;
  float s = 0.f, q = 0.f;
  for (int r = t; r < N_GRAPHS; r += 256) { float v = x[r * ld + c]; s += v; q += v * v; }
  ssum[t] = s; ssq[t] = q; __syncthreads();
  for (int off = 128; off > 0; off >>= 1) {
    if (t < off) { ssum[t] += ssum[t + off]; ssq[t] += ssq[t + off]; }
    __syncthreads();
  }
  if (t == 0) {
    float m = ssum[0] / (float)N_GRAPHS;
    float var = ssq[0] / (float)N_GRAPHS - m * m;
    mu[c] = m;
    rstd[c] = rsqrtf(var + EPS);
  }
}

// ---------- y2 = relu(bn1(y1)) @ Wf2 + bf2 ----------
__global__ void k_mlp2(const float* __restrict__ y1, const float* __restrict__ mu1,
                       const float* __restrict__ rstd1, const float* __restrict__ g1,
                       const float* __restrict__ be1, const float* __restrict__ Wf2,
                       const float* __restrict__ bf2, float* __restrict__ y2) {
  int idx = blockIdx.x * 256 + threadIdx.x;   // 1024*32
  int g = idx >> 5, o = idx & 31;
  float acc = bf2[o];
  for (int k = 0; k < DF1; k++) {
    float x = (y1[g * DF1 + k] - mu1[k]) * rstd1[k] * g1[k] + be1[k];
    x = fmaxf(x, 0.f);
    acc += x * Wf2[k * DF2 + o];
  }
  y2[g * DF2 + o] = acc;
}

// ---------- out = relu(bn2(y2)) @ Wf3 + bf3 ----------
__global__ void k_mlp3(const float* __restrict__ y2, const float* __restrict__ mu2,
                       const float* __restrict__ rstd2, const float* __restrict__ g2,
                       const float* __restrict__ be2, const float* __restrict__ Wf3,
                       const float* __restrict__ bf3, float* __restrict__ out) {
  int idx = blockIdx.x * 256 + threadIdx.x;   // 1024*8
  int g = idx >> 3, o = idx & 7;
  float acc = bf3[o];
  for (int k = 0; k < DF2; k++) {
    float x = (y2[g * DF2 + k] - mu2[k]) * rstd2[k] * g2[k] + be2[k];
    x = fmaxf(x, 0.f);
    acc += x * Wf3[k * DOUT + o];
  }
  out[g * DOUT + o] = acc;
}

extern "C" void kernel_launch(void* const* d_in, const int* in_sizes, int n_in,
                              void* d_out, int out_size, void* d_ws, size_t ws_size,
                              hipStream_t stream) {
  const float* feat = (const float*)d_in[0];
  const float* sf   = (const float*)d_in[1];
  const int*   src  = (const int*)d_in[2];
  const int*   dst  = (const int*)d_in[3];
  const int*   n2g  = (const int*)d_in[4];
  const float* W1   = (const float*)d_in[5];
  const float* b1   = (const float*)d_in[6];
  const float* W2   = (const float*)d_in[7];
  const float* b2   = (const float*)d_in[8];
  const float* Wf1  = (const float*)d_in[9];
  const float* bf1  = (const float*)d_in[10];
  const float* g1   = (const float*)d_in[11];
  const float* be1  = (const float*)d_in[12];
  const float* Wf2  = (const float*)d_in[13];
  const float* bf2  = (const float*)d_in[14];
  const float* g2   = (const float*)d_in[15];
  const float* be2  = (const float*)d_in[16];
  const float* Wf3  = (const float*)d_in[17];
  const float* bf3  = (const float*)d_in[18];
  float* out = (float*)d_out;

  char* ws = (char*)d_ws;
  size_t off = 0;
  auto alloc = [&](size_t bytes) -> void* {
    void* p = ws + off;
    off = (off + bytes + 255) & ~(size_t)255;
    return p;
  };
  // zero-init region first (deg, gcnt, hg_sum) — one memset covers it
  int*    deg     = (int*)alloc(N_NODES * 4);
  int*    gcnt    = (int*)alloc(N_GRAPHS * 4);
  float*  hg_sum  = (float*)alloc(N_GRAPHS * D2 * 4);
  size_t zero_bytes = off;
  int*    row_off = (int*)alloc(N_NODES * 4);
  int*    cursor  = (int*)alloc(N_NODES * 4);
  int*    blocksum= (int*)alloc(64 * 4);
  int*    blockoff= (int*)alloc(64 * 4);
  int*    csr     = (int*)alloc((size_t)N_EDGES * 4);
  __half* p1h     = (__half*)alloc((size_t)N_NODES * D1 * 2);
  __half* p2h     = (__half*)alloc((size_t)N_NODES * D2 * 2);
  float*  y1      = (float*)alloc((size_t)N_GRAPHS * DF1 * 4);
  float*  y2      = (float*)alloc((size_t)N_GRAPHS * DF2 * 4);
  float*  mu1     = (float*)alloc(DF1 * 4);
  float*  rstd1   = (float*)alloc(DF1 * 4);
  float*  mu2     = (float*)alloc(DF2 * 4);
  float*  rstd2   = (float*)alloc(DF2 * 4);

  hipMemsetAsync(d_ws, 0, zero_bytes, stream);

  k_count<<<N_EDGES / 256, 256, 0, stream>>>(dst, deg);
  k_scan1<<<SCAN_NB, 256, 0, stream>>>(deg, blocksum);
  k_scan2<<<1, 64, 0, stream>>>(blocksum, blockoff);
  k_scan3<<<SCAN_NB, 256, 0, stream>>>(deg, blockoff, row_off, cursor);
  k_scatter<<<N_EDGES / 256, 256, 0, stream>>>(src, dst, cursor, csr);
  k_gemm1<<<N_NODES / 40, 256, 0, stream>>>(feat, W1, p1h);
  k_agg1<<<N_NODES / 4, 256, 0, stream>>>(p1h, deg, row_off, csr, b1, W2, p2h);
  k_agg2<<<(N_NODES * D2 + 255) / 256, 256, 0, stream>>>(p2h, deg, row_off, csr, b2, n2g, hg_sum, gcnt);
  k_mlp1<<<N_GRAPHS, 128, 0, stream>>>(hg_sum, gcnt, sf, Wf1, bf1, y1);
  k_bnstats<<<DF1, 256, 0, stream>>>(y1, DF1, mu1, rstd1);
  k_mlp2<<<(N_GRAPHS * DF2) / 256, 256, 0, stream>>>(y1, mu1, rstd1, g1, be1, Wf2, bf2, y2);
  k_bnstats<<<DF2, 256, 0, stream>>>(y2, DF2, mu2, rstd2);
  k_mlp3<<<(N_GRAPHS * DOUT) / 256, 256, 0, stream>>>(y2, mu2, rstd2, g2, be2, Wf3, bf3, out);
}

// Round 3
// 469.581 us; speedup vs baseline: 1.4880x; 1.3652x over previous
//
#include <hip/hip_runtime.h>
#include <hip/hip_fp16.h>

#define N_NODES 100000
#define N_EDGES 1600000
#define N_GRAPHS 1024
#define DIM_IN 128
#define D1 100
#define D2 20
#define DIM_SF 32
#define DF1 128
#define DF2 32
#define DOUT 8
#define EPS 1e-5f

// ---------------- bucket-sort CSR build ----------------
#define NBK 512                 // buckets
#define BW 196                  // nodes per bucket (512*196 = 100352 >= N_NODES)
#define EPB 4096                // edges per block in pass 1
#define NBLK1 ((N_EDGES + EPB - 1) / EPB)   // 391

// pass 1a: per-(block,bucket) histogram. No global atomics.
__global__ void __launch_bounds__(256) k_bcount(const int* __restrict__ dst,
                                                int* __restrict__ counts) {
  __shared__ int hist[NBK];
  int t = threadIdx.x, blk = blockIdx.x;
  for (int i = t; i < NBK; i += 256) hist[i] = 0;
  __syncthreads();
  int base = blk * EPB;
#pragma unroll
  for (int r = 0; r < 16; r++) {
    int e = base + r * 256 + t;
    if (e < N_EDGES) {
      unsigned b = (unsigned)dst[e] / BW;
      atomicAdd(&hist[b], 1);
    }
  }
  __syncthreads();
  for (int i = t; i < NBK; i += 256) counts[blk * NBK + i] = hist[i];
}

// pass 1b: for each bucket, exclusive scan of counts across blocks. 1 wave/bucket.
__global__ void __launch_bounds__(64) k_bscanA(const int* __restrict__ counts,
                                               int* __restrict__ offs,
                                               int* __restrict__ totals) {
  int b = blockIdx.x, l = threadIdx.x;
  int carry = 0;
  for (int chunk = 0; chunk < NBLK1; chunk += 64) {
    int blk = chunk + l;
    int v = (blk < NBLK1) ? counts[blk * NBK + b] : 0;
    int incl = v;
    for (int s = 1; s < 64; s <<= 1) { int x = __shfl_up(incl, s); if (l >= s) incl += x; }
    if (blk < NBLK1) offs[blk * NBK + b] = carry + incl - v;
    carry += __shfl(incl, 63);
  }
  if (l == 0) totals[b] = carry;
}

// pass 1c: exclusive scan of bucket totals -> bucket base offsets (513 entries).
__global__ void __launch_bounds__(512) k_bscanB(const int* __restrict__ totals,
                                                int* __restrict__ bin_base) {
  __shared__ int lds[NBK];
  int t = threadIdx.x;
  int v = totals[t];
  lds[t] = v; __syncthreads();
  for (int s = 1; s < NBK; s <<= 1) {
    int x = (t >= s) ? lds[t - s] : 0;
    __syncthreads();
    lds[t] += x;
    __syncthreads();
  }
  bin_base[t] = lds[t] - v;
  if (t == NBK - 1) bin_base[NBK] = lds[t];
}

// pass 1d: scatter packed (src<<8 | local_dst) into bucket-ordered array.
// LDS-staged in bucket-major order so write-out is runs of contiguous lines.
__global__ void __launch_bounds__(256) k_bscatter(const int* __restrict__ src,
                                                  const int* __restrict__ dst,
                                                  const int* __restrict__ offs,
                                                  const int* __restrict__ bin_base,
                                                  unsigned* __restrict__ packed_out) {
  __shared__ int hist[NBK];
  __shared__ int lbase[NBK];
  __shared__ int gbase[NBK];
  __shared__ int ssum[256];
  __shared__ unsigned sval[EPB];   // 16 KB
  __shared__ int spos[EPB];        // 16 KB
  int t = threadIdx.x, blk = blockIdx.x;
  for (int i = t; i < NBK; i += 256) hist[i] = 0;
  __syncthreads();
  int base = blk * EPB;
  unsigned pk[16]; int bn[16]; int rk[16];
#pragma unroll
  for (int r = 0; r < 16; r++) {
    int e = base + r * 256 + t;
    bn[r] = -1;
    if (e < N_EDGES) {
      int dv = dst[e];
      unsigned b = (unsigned)dv / BW;
      unsigned ld = (unsigned)dv - b * BW;
      bn[r] = (int)b;
      pk[r] = ((unsigned)src[e] << 8) | ld;
      rk[r] = atomicAdd(&hist[b], 1);
    }
  }
  __syncthreads();
  // exclusive scan of hist[512] with 256 threads (2 bins each)
  int h0 = hist[2 * t], h1 = hist[2 * t + 1];
  int s = h0 + h1;
  ssum[t] = s; __syncthreads();
  for (int off = 1; off < 256; off <<= 1) {
    int x = (t >= off) ? ssum[t - off] : 0;
    __syncthreads();
    ssum[t] += x;
    __syncthreads();
  }
  int excl = ssum[t] - s;
  lbase[2 * t] = excl;
  lbase[2 * t + 1] = excl + h0;
  gbase[2 * t]     = bin_base[2 * t]     + offs[blk * NBK + 2 * t];
  gbase[2 * t + 1] = bin_base[2 * t + 1] + offs[blk * NBK + 2 * t + 1];
  __syncthreads();
#pragma unroll
  for (int r = 0; r < 16; r++) {
    if (bn[r] >= 0) {
      int li = lbase[bn[r]] + rk[r];
      sval[li] = pk[r];
      spos[li] = gbase[bn[r]] + rk[r];
    }
  }
  __syncthreads();
  int cnt = N_EDGES - base; if (cnt > EPB) cnt = EPB;
  for (int i = t; i < cnt; i += 256) packed_out[spos[i]] = sval[i];
}

// pass 2: one block per bucket. Sort within bucket in LDS, emit exact CSR,
// deg and row_off. All global reads/writes coalesced.
__global__ void __launch_bounds__(256) k_bfine(const unsigned* __restrict__ packed_in,
                                               const int* __restrict__ bin_base,
                                               int* __restrict__ csr,
                                               int* __restrict__ deg,
                                               int* __restrict__ row_off) {
  __shared__ unsigned sval[EPB];   // 16 KB
  __shared__ int scsr[EPB];        // 16 KB
  __shared__ int hist[256];
  __shared__ int soff[256];
  __shared__ int cur[256];
  int b = blockIdx.x, t = threadIdx.x;
  int start = bin_base[b];
  int cnt = bin_base[b + 1] - start;
  if (cnt > EPB) cnt = EPB;
  hist[t] = 0;
  __syncthreads();
  for (int i = t; i < cnt; i += 256) {
    unsigned v = packed_in[start + i];
    sval[i] = v;
    atomicAdd(&hist[v & 255u], 1);
  }
  __syncthreads();
  int h = hist[t];
  soff[t] = h; __syncthreads();
  for (int off = 1; off < 256; off <<= 1) {
    int x = (t >= off) ? soff[t - off] : 0;
    __syncthreads();
    soff[t] += x;
    __syncthreads();
  }
  int excl = soff[t] - h;
  cur[t] = excl;
  int n = b * BW + t;
  if (t < BW && n < N_NODES) { deg[n] = h; row_off[n] = start + excl; }
  __syncthreads();
  for (int i = t; i < cnt; i += 256) {
    unsigned v = sval[i];
    int pos = atomicAdd(&cur[v & 255u], 1);
    scsr[pos] = (int)(v >> 8);
  }
  __syncthreads();
  for (int i = t; i < cnt; i += 256) csr[start + i] = scsr[i];
}

// ---------------- p1 = fp16(feat @ W1)  (bias applied after aggregation) ----------------
__global__ void __launch_bounds__(256) k_gemm1(const float* __restrict__ feat,
                                               const float* __restrict__ W1,
                                               __half* __restrict__ p1h) {
  __shared__ float w1s[DIM_IN * D1];   // 51.2 KB
  int t = threadIdx.x;
  for (int i = t; i < DIM_IN * D1; i += 256) w1s[i] = W1[i];
  __syncthreads();
  if (t >= 250) return;
  int q = t % 25, ng = t / 25;
  int n0 = blockIdx.x * 40 + ng * 4;   // grid 2500 -> exactly 100000 nodes
  int c0 = q * 4;
  float acc[4][4] = {{0.f}};
  const float* f0 = feat + (size_t)n0 * DIM_IN;
  for (int k = 0; k < DIM_IN; k += 4) {
    float4 w0 = *(const float4*)&w1s[(k + 0) * D1 + c0];
    float4 w1 = *(const float4*)&w1s[(k + 1) * D1 + c0];
    float4 w2 = *(const float4*)&w1s[(k + 2) * D1 + c0];
    float4 w3 = *(const float4*)&w1s[(k + 3) * D1 + c0];
#pragma unroll
    for (int j = 0; j < 4; j++) {
      float4 f = *(const float4*)(f0 + j * DIM_IN + k);
      acc[j][0] += f.x * w0.x + f.y * w1.x + f.z * w2.x + f.w * w3.x;
      acc[j][1] += f.x * w0.y + f.y * w1.y + f.z * w2.y + f.w * w3.y;
      acc[j][2] += f.x * w0.z + f.y * w1.z + f.z * w2.z + f.w * w3.z;
      acc[j][3] += f.x * w0.w + f.y * w1.w + f.z * w2.w + f.w * w3.w;
    }
  }
#pragma unroll
  for (int j = 0; j < 4; j++) {
    __half2* d2 = (__half2*)(p1h + (size_t)(n0 + j) * D1 + c0);
    d2[0] = __floats2half2_rn(acc[j][0], acc[j][1]);
    d2[1] = __floats2half2_rn(acc[j][2], acc[j][3]);
  }
}

// ---------- agg1 (mean of fp16 p1 over in-edges) + b1 + relu + GEMM2 -> fp16 p2 ----------
__global__ void __launch_bounds__(256) k_agg1(const __half* __restrict__ p1h,
                                              const int* __restrict__ deg,
                                              const int* __restrict__ row_off,
                                              const int* __restrict__ csr,
                                              const float* __restrict__ b1,
                                              const float* __restrict__ W2,
                                              __half* __restrict__ p2h) {
  __shared__ float w2s[D1 * D2];
  __shared__ float b1s[D1];
  __shared__ float hbuf[4][104];
  int t = threadIdx.x;
  for (int i = t; i < D1 * D2; i += 256) w2s[i] = W2[i];
  if (t < D1) b1s[t] = b1[t];
  __syncthreads();
  int w = t >> 6, lane = t & 63;
  int n = blockIdx.x * 4 + w;
  int d = deg[n], ro = row_off[n];
  bool act = lane < 50;
  float ax = 0.f, ay = 0.f;
  if (d > 0) {
    for (int base = 0; base < d; base += 64) {
      int m = d - base; if (m > 64) m = 64;
      int sv = (lane < m) ? csr[ro + base + lane] : 0;
      int j = 0;
      for (; j + 3 < m; j += 4) {
        int s0 = __shfl(sv, j), s1 = __shfl(sv, j + 1);
        int s2 = __shfl(sv, j + 2), s3 = __shfl(sv, j + 3);
        if (act) {
          float2 v0 = __half22float2(((const __half2*)(p1h + (size_t)s0 * D1))[lane]);
          float2 v1 = __half22float2(((const __half2*)(p1h + (size_t)s1 * D1))[lane]);
          float2 v2 = __half22float2(((const __half2*)(p1h + (size_t)s2 * D1))[lane]);
          float2 v3 = __half22float2(((const __half2*)(p1h + (size_t)s3 * D1))[lane]);
          ax += (v0.x + v1.x) + (v2.x + v3.x);
          ay += (v0.y + v1.y) + (v2.y + v3.y);
        }
      }
      for (; j < m; j++) {
        int s0 = __shfl(sv, j);
        if (act) {
          float2 v0 = __half22float2(((const __half2*)(p1h + (size_t)s0 * D1))[lane]);
          ax += v0.x; ay += v0.y;
        }
      }
    }
    float inv = 1.0f / (float)d;
    ax *= inv; ay *= inv;
  } else if (act) {
    float2 v = __half22float2(((const __half2*)(p1h + (size_t)n * D1))[lane]);
    ax = v.x; ay = v.y;
  }
  if (act) {
    int c = lane * 2;
    hbuf[w][c]     = fmaxf(ax + b1s[c], 0.f);
    hbuf[w][c + 1] = fmaxf(ay + b1s[c + 1], 0.f);
  }
  __syncthreads();
  if (lane < D2) {
    float acc = 0.f;
#pragma unroll 4
    for (int c = 0; c < D1; c++) acc += hbuf[w][c] * w2s[c * D2 + lane];
    p2h[(size_t)n * D2 + lane] = __float2half_rn(acc);
  }
}

// ---------- agg2 (mean of fp16 p2) + b2 + relu + graph-pool atomics ----------
__global__ void k_agg2(const __half* __restrict__ p2h, const int* __restrict__ deg,
                       const int* __restrict__ row_off, const int* __restrict__ csr,
                       const float* __restrict__ b2, const int* __restrict__ n2g,
                       float* __restrict__ hg_sum, int* __restrict__ gcnt) {
  int idx = blockIdx.x * 256 + threadIdx.x;
  int n = idx / D2, c = idx % D2;
  if (n >= N_NODES) return;
  int d = deg[n], ro = row_off[n];
  float acc = 0.f;
  if (d > 0) {
    float a0 = 0.f, a1 = 0.f, a2 = 0.f, a3 = 0.f;
    int e = 0;
    for (; e + 3 < d; e += 4) {
      int s0 = csr[ro + e],     s1 = csr[ro + e + 1];
      int s2 = csr[ro + e + 2], s3 = csr[ro + e + 3];
      a0 += __half2float(p2h[(size_t)s0 * D2 + c]);
      a1 += __half2float(p2h[(size_t)s1 * D2 + c]);
      a2 += __half2float(p2h[(size_t)s2 * D2 + c]);
      a3 += __half2float(p2h[(size_t)s3 * D2 + c]);
    }
    for (; e < d; e++) a0 += __half2float(p2h[(size_t)csr[ro + e] * D2 + c]);
    acc = ((a0 + a1) + (a2 + a3)) / (float)d;
  } else {
    acc = __half2float(p2h[(size_t)n * D2 + c]);
  }
  float v = fmaxf(acc + b2[c], 0.f);
  int g = n2g[n];
  atomicAdd(&hg_sum[g * D2 + c], v);
  if (c == 0) atomicAdd(&gcnt[g], 1);
}

// ---------- head ----------
__global__ void __launch_bounds__(128) k_mlp1(const float* __restrict__ hg_sum,
                                              const int* __restrict__ gcnt,
                                              const float* __restrict__ sf,
                                              const float* __restrict__ Wf1,
                                              const float* __restrict__ bf1,
                                              float* __restrict__ y1) {
  __shared__ float prod[D2 * DIM_SF];
  __shared__ float hgl[D2], sfl[DIM_SF];
  int g = blockIdx.x, t = threadIdx.x;
  float cnt = (float)gcnt[g]; if (cnt < 1.f) cnt = 1.f;
  if (t < D2) hgl[t] = hg_sum[g * D2 + t] / cnt;
  if (t < DIM_SF) sfl[t] = sf[g * DIM_SF + t];
  __syncthreads();
  for (int i = t; i < D2 * DIM_SF; i += 128) prod[i] = hgl[i >> 5] * sfl[i & 31];
  __syncthreads();
  float acc = bf1[t];
#pragma unroll 4
  for (int k = 0; k < D2 * DIM_SF; k++) acc += prod[k] * Wf1[k * DF1 + t];
  y1[g * DF1 + t] = acc;
}

__global__ void k_bnstats(const float* __restrict__ x, int ld,
                          float* __restrict__ mu, float* __restrict__ rstd) {
  __shared__ float ssum[256], ssq[256];
  int c = blockIdx.x, t = threadIdx.x;
  float s = 0.f, q = 0.f;
  for (int r = t; r < N_GRAPHS; r += 256) { float v = x[r * ld + c]; s += v; q += v * v; }
  ssum[t] = s; ssq[t] = q; __syncthreads();
  for (int off = 128; off > 0; off >>= 1) {
    if (t < off) { ssum[t] += ssum[t + off]; ssq[t] += ssq[t + off]; }
    __syncthreads();
  }
  if (t == 0) {
    float m = ssum[0] / (float)N_GRAPHS;
    float var = ssq[0] / (float)N_GRAPHS - m * m;
    mu[c] = m;
    rstd[c] = rsqrtf(var + EPS);
  }
}

__global__ void k_mlp2(const float* __restrict__ y1, const float* __restrict__ mu1,
                       const float* __restrict__ rstd1, const float* __restrict__ g1,
                       const float* __restrict__ be1, const float* __restrict__ Wf2,
                       const float* __restrict__ bf2, float* __restrict__ y2) {
  int idx = blockIdx.x * 256 + threadIdx.x;
  int g = idx >> 5, o = idx & 31;
  float acc = bf2[o];
  for (int k = 0; k < DF1; k++) {
    float x = (y1[g * DF1 + k] - mu1[k]) * rstd1[k] * g1[k] + be1[k];
    x = fmaxf(x, 0.f);
    acc += x * Wf2[k * DF2 + o];
  }
  y2[g * DF2 + o] = acc;
}

__global__ void k_mlp3(const float* __restrict__ y2, const float* __restrict__ mu2,
                       const float* __restrict__ rstd2, const float* __restrict__ g2,
                       const float* __restrict__ be2, const float* __restrict__ Wf3,
                       const float* __restrict__ bf3, float* __restrict__ out) {
  int idx = blockIdx.x * 256 + threadIdx.x;
  int g = idx >> 3, o = idx & 7;
  float acc = bf3[o];
  for (int k = 0; k < DF2; k++) {
    float x = (y2[g * DF2 + k] - mu2[k]) * rstd2[k] * g2[k] + be2[k];
    x = fmaxf(x, 0.f);
    acc += x * Wf3[k * DOUT + o];
  }
  out[g * DOUT + o] = acc;
}

extern "C" void kernel_launch(void* const* d_in, const int* in_sizes, int n_in,
                              void* d_out, int out_size, void* d_ws, size_t ws_size,
                              hipStream_t stream) {
  const float* feat = (const float*)d_in[0];
  const float* sf   = (const float*)d_in[1];
  const int*   src  = (const int*)d_in[2];
  const int*   dst  = (const int*)d_in[3];
  const int*   n2g  = (const int*)d_in[4];
  const float* W1   = (const float*)d_in[5];
  const float* b1   = (const float*)d_in[6];
  const float* W2   = (const float*)d_in[7];
  const float* b2   = (const float*)d_in[8];
  const float* Wf1  = (const float*)d_in[9];
  const float* bf1  = (const float*)d_in[10];
  const float* g1   = (const float*)d_in[11];
  const float* be1  = (const float*)d_in[12];
  const float* Wf2  = (const float*)d_in[13];
  const float* bf2  = (const float*)d_in[14];
  const float* g2   = (const float*)d_in[15];
  const float* be2  = (const float*)d_in[16];
  const float* Wf3  = (const float*)d_in[17];
  const float* bf3  = (const float*)d_in[18];
  float* out = (float*)d_out;

  char* ws = (char*)d_ws;
  size_t off = 0;
  auto alloc = [&](size_t bytes) -> void* {
    void* p = ws + off;
    off = (off + bytes + 255) & ~(size_t)255;
    return p;
  };
  // zero-init region first (gcnt, hg_sum)
  int*      gcnt     = (int*)alloc(N_GRAPHS * 4);
  float*    hg_sum   = (float*)alloc(N_GRAPHS * D2 * 4);
  size_t zero_bytes = off;
  int*      deg      = (int*)alloc(N_NODES * 4);
  int*      row_off  = (int*)alloc(N_NODES * 4);
  int*      counts   = (int*)alloc((size_t)NBLK1 * NBK * 4);
  int*      offs     = (int*)alloc((size_t)NBLK1 * NBK * 4);
  int*      totals   = (int*)alloc(NBK * 4);
  int*      bin_base = (int*)alloc((NBK + 1) * 4);
  unsigned* packed   = (unsigned*)alloc((size_t)N_EDGES * 4);
  int*      csr      = (int*)alloc((size_t)N_EDGES * 4);
  __half*   p1h      = (__half*)alloc((size_t)N_NODES * D1 * 2);
  __half*   p2h      = (__half*)alloc((size_t)N_NODES * D2 * 2);
  float*    y1       = (float*)alloc((size_t)N_GRAPHS * DF1 * 4);
  float*    y2       = (float*)alloc((size_t)N_GRAPHS * DF2 * 4);
  float*    mu1      = (float*)alloc(DF1 * 4);
  float*    rstd1    = (float*)alloc(DF1 * 4);
  float*    mu2      = (float*)alloc(DF2 * 4);
  float*    rstd2    = (float*)alloc(DF2 * 4);

  hipMemsetAsync(d_ws, 0, zero_bytes, stream);

  k_bcount<<<NBLK1, 256, 0, stream>>>(dst, counts);
  k_bscanA<<<NBK, 64, 0, stream>>>(counts, offs, totals);
  k_bscanB<<<1, NBK, 0, stream>>>(totals, bin_base);
  k_bscatter<<<NBLK1, 256, 0, stream>>>(src, dst, offs, bin_base, packed);
  k_bfine<<<NBK, 256, 0, stream>>>(packed, bin_base, csr, deg, row_off);
  k_gemm1<<<N_NODES / 40, 256, 0, stream>>>(feat, W1, p1h);
  k_agg1<<<N_NODES / 4, 256, 0, stream>>>(p1h, deg, row_off, csr, b1, W2, p2h);
  k_agg2<<<(N_NODES * D2 + 255) / 256, 256, 0, stream>>>(p2h, deg, row_off, csr, b2, n2g, hg_sum, gcnt);
  k_mlp1<<<N_GRAPHS, 128, 0, stream>>>(hg_sum, gcnt, sf, Wf1, bf1, y1);
  k_bnstats<<<DF1, 256, 0, stream>>>(y1, DF1, mu1, rstd1);
  k_mlp2<<<(N_GRAPHS * DF2) / 256, 256, 0, stream>>>(y1, mu1, rstd1, g1, be1, Wf2, bf2, y2);
  k_bnstats<<<DF2, 256, 0, stream>>>(y2, DF2, mu2, rstd2);
  k_mlp3<<<(N_GRAPHS * DOUT) / 256, 256, 0, stream>>>(y2, mu2, rstd2, g2, be2, Wf3, bf3, out);
}